// Round 1
// baseline (575.334 us; speedup 1.0000x reference)
//
#include <hip/hip_runtime.h>
#include <math.h>

// CRITICAL: no FMA contraction anywhere — we are bit-replicating numpy's
// SSE (no-FMA) float32 einsum inner loop.
#pragma clang fp contract(off)

#define T_TOKENS 16384
#define HDIM 2048
#define NEXP 64
#define TOPK 6
#define SEQ 4096
#define TPB 64              // tokens per block (= one wavefront width)
#define KC 128              // k-chunk (floats)
#define NC (HDIM / KC)      // 16 chunks
#define LGS 65              // padded stride for logits
#define PS 65               // padded stride for probs

// numpy einsum contig_two micro-step (SSE3 baseline, 4 lanes, no FMA):
// per 16-element block: vacc[l] = a0[l]*b0[l] + (a1[l]*b1[l] + (a2[l]*b2[l] + (a3[l]*b3[l] + vacc[l])))
__device__ __forceinline__ void np_upd(const float4& w0, const float4& w1,
                                       const float4& w2, const float4& w3,
                                       const float4& x0, const float4& x1,
                                       const float4& x2, const float4& x3,
                                       float acc[4])
{
    acc[0] = w0.x*x0.x + (w1.x*x1.x + (w2.x*x2.x + (w3.x*x3.x + acc[0])));
    acc[1] = w0.y*x0.y + (w1.y*x1.y + (w2.y*x2.y + (w3.y*x3.y + acc[1])));
    acc[2] = w0.z*x0.z + (w1.z*x1.z + (w2.z*x2.z + (w3.z*x3.z + acc[2])));
    acc[3] = w0.w*x0.w + (w1.w*x1.w + (w2.w*x2.w + (w3.w*x3.w + acc[3])));
}

__global__ __launch_bounds__(512, 2) void moe_gate_main(
    const float* __restrict__ x, const float* __restrict__ wgt,
    float* __restrict__ out, float* __restrict__ gacc)
{
    // x tile [64 tokens][128 k], double-buffered, XOR-swizzled (16B slot ^= row&7): 64 KB.
    __shared__ __attribute__((aligned(16))) float xs[2 * TPB * KC];
    // Epilogue scratch overlaid on xs. Safety: lg (buf0 region) is only written
    // after a wave finishes its own k-loop (other waves can then only be in the
    // LAST chunk's compute, which reads buf1) — disjoint. probs/psum/cnt are only
    // touched after full barriers.
    float* lg    = xs;                  // [64][65]  floats [0, 4160)
    float* probs = xs + 4224;           // [64][65]  floats [4224, 8384)
    float* psum  = xs + 8448;           // [8][64]   floats [8448, 8960)
    int*   cnt   = (int*)(xs + 8960);   // [64]      floats [8960, 9024)

    const int tid  = threadIdx.x;
    const int bid  = blockIdx.x;
    const int tb   = bid * TPB;
    const int b    = bid >> 6;          // 64 blocks per batch row (4096/64)
    const int lane = tid & 63;          // token row within tile
    const int wv   = tid >> 6;          // wave id -> 8-expert group

    // Wave-uniform expert base: forces scalar (SGPR) addressing for W loads.
    const int ebase = __builtin_amdgcn_readfirstlane(wv * 8);
    const float* wbase = wgt + (size_t)ebase * HDIM;

    float acc[8][4];
    #pragma unroll
    for (int e = 0; e < 8; ++e)
        #pragma unroll
        for (int l = 0; l < 4; ++l) acc[e][l] = 0.f;

    // staging geometry: 512 thr x 4 rounds x 16 B = 32 KB chunk.
    // physical 16B slot p -> (row = p>>5, ps = p&31); holds logical slot ls = ps ^ (row&7).
    size_t goff[4]; int loff[4];
    #pragma unroll
    for (int r = 0; r < 4; ++r) {
        const int p   = r * 512 + tid;
        const int row = p >> 5;
        const int ps  = p & 31;
        const int ls  = ps ^ (row & 7);
        goff[r] = (size_t)(tb + row) * HDIM + ls * 4;
        loff[r] = p * 4;
    }

    // preload chunk 0 into regs
    float4 tmp[4];
    #pragma unroll
    for (int r = 0; r < 4; ++r)
        tmp[r] = *reinterpret_cast<const float4*>(&x[goff[r]]);

    const int s16 = (lane & 7) << 4;    // read-side swizzle (byte XOR)
    const char* xrow0 = reinterpret_cast<const char*>(xs) + lane * (KC * 4);

    for (int c = 0; c < NC; ++c) {
        // write staged chunk c (conflict-free: consecutive 16B per lane)
        float* dst = xs + (c & 1) * (TPB * KC);
        #pragma unroll
        for (int r = 0; r < 4; ++r)
            *reinterpret_cast<float4*>(&dst[loff[r]]) = tmp[r];
        __syncthreads();   // single barrier per chunk: separates writes(buf) from reads(buf)

        // issue loads for chunk c+1 AFTER the barrier so they stay in flight
        // under the whole compute phase (no pre-barrier vmcnt(0) drain).
        if (c + 1 < NC) {
            const int k0 = (c + 1) * KC;
            #pragma unroll
            for (int r = 0; r < 4; ++r)
                tmp[r] = *reinterpret_cast<const float4*>(&x[goff[r] + k0]);
        }

        const char* xrow = xrow0 + (c & 1) * (TPB * KC * 4);
        const float* wc = wbase + c * KC;
        #pragma unroll
        for (int kk = 0; kk < KC / 16; ++kk) {
            // lane's own token row: 16 floats, swizzled slots, reused across 8 experts
            float4 xa[4];
            #pragma unroll
            for (int j = 0; j < 4; ++j)
                xa[j] = *reinterpret_cast<const float4*>(xrow + ((((kk * 4 + j) << 4)) ^ s16));
            #pragma unroll
            for (int e = 0; e < 8; ++e) {
                const float* wr = wc + (size_t)e * HDIM + kk * 16;  // wave-uniform address
                const float4 w0 = *reinterpret_cast<const float4*>(wr);
                const float4 w1 = *reinterpret_cast<const float4*>(wr + 4);
                const float4 w2 = *reinterpret_cast<const float4*>(wr + 8);
                const float4 w3 = *reinterpret_cast<const float4*>(wr + 12);
                np_upd(w0, w1, w2, w3, xa[0], xa[1], xa[2], xa[3], acc[e]);
            }
        }
    }

    // horizontal reduce exactly like npyv_sum_f32 (SSE3 hadd): (v0+v1)+(v2+v3)
    #pragma unroll
    for (int e = 0; e < 8; ++e) {
        float v = (acc[e][0] + acc[e][1]) + (acc[e][2] + acc[e][3]);
        lg[lane * LGS + ebase + e] = v;
    }
    __syncthreads();

    // ---- softmax per token (threads 0..63), fp32 like np
    if (tid < TPB) {
        const int t = tid;
        float mx = lg[t * LGS];
        for (int e = 1; e < NEXP; ++e) { float v = lg[t * LGS + e]; if (v > mx) mx = v; }
        for (int e = 0; e < NEXP; ++e)
            probs[t * PS + e] = expf(lg[t * LGS + e] - mx);
        // numpy pairwise sum, n=64: 8 strided accumulators then paired combine
        float r[8];
        #pragma unroll
        for (int j = 0; j < 8; ++j) r[j] = probs[t * PS + j];
        for (int i = 8; i < 64; i += 8)
            #pragma unroll
            for (int j = 0; j < 8; ++j) r[j] += probs[t * PS + i + j];
        float S = ((r[0] + r[1]) + (r[2] + r[3])) + ((r[4] + r[5]) + (r[6] + r[7]));
        for (int e = 0; e < NEXP; ++e) probs[t * PS + e] = probs[t * PS + e] / S;
    } else if (tid < 128) {
        cnt[tid - 64] = 0;   // cnt lives in buf1 region: only safe after the barrier above
    }
    __syncthreads();

    // ---- partial per-expert score sums (aux loss), all 512 threads
    {
        const int e = tid & 63, q = tid >> 6;
        float s = 0.f;
        for (int t = q * 8; t < q * 8 + 8; ++t) s += probs[t * PS + e];
        psum[q * 64 + e] = s;
    }
    __syncthreads();

    if (tid < TPB) {
        // ---- top-6 on fp32 probs, strict > ascending scan (tie -> lowest index)
        const int t = tid;
        const int gt = tb + t;
        float pv[TOPK]; int pi[TOPK];
        for (int r = 0; r < TOPK; ++r) {
            float bv = -1.f; int be = 0;
            for (int e = 0; e < NEXP; ++e) {
                float v = probs[t * PS + e];
                if (v > bv) { bv = v; be = e; }
            }
            probs[t * PS + be] = -1.f;
            pv[r] = bv; pi[r] = be;
            atomicAdd(&cnt[be], 1);
        }
        float wsum = pv[0];
        #pragma unroll
        for (int r = 1; r < TOPK; ++r) wsum += pv[r];
        wsum += 1e-20f;
        #pragma unroll
        for (int r = 0; r < TOPK; ++r) {
            out[(size_t)gt * TOPK + r] = (float)pi[r];
            out[(size_t)T_TOKENS * TOPK + (size_t)gt * TOPK + r] = pv[r] / wsum;
        }
    } else if (tid < 128) {
        const int e = tid - 64;
        float s = 0.f;
        #pragma unroll
        for (int q = 0; q < 8; ++q) s += psum[q * 64 + e];
        atomicAdd(&gacc[b * 64 + e], s);
    }
    __syncthreads();
    if (tid < NEXP) {
        atomicAdd(&gacc[256 + b * 64 + tid], (float)cnt[tid]);
    }
}

__global__ __launch_bounds__(256) void moe_gate_aux(
    const float* __restrict__ gacc, float* __restrict__ out)
{
    __shared__ float red[4];
    const int tid = threadIdx.x;
    float v = gacc[256 + tid] * gacc[tid];
    #pragma unroll
    for (int o = 32; o > 0; o >>= 1) v += __shfl_down(v, o, 64);
    if ((tid & 63) == 0) red[tid >> 6] = v;
    __syncthreads();
    if (tid == 0) {
        float tot = red[0] + red[1] + red[2] + red[3];
        const float scale = (64.0f / (4096.0f * 6.0f)) / 4096.0f;
        out[2 * T_TOKENS * TOPK] = 1e-3f * (tot * scale) * 0.25f;
    }
}

extern "C" void kernel_launch(void* const* d_in, const int* in_sizes, int n_in,
                              void* d_out, int out_size, void* d_ws, size_t ws_size,
                              hipStream_t stream) {
    const float* x   = (const float*)d_in[0];
    const float* wgt = (const float*)d_in[1];
    float* out  = (float*)d_out;
    float* gacc = (float*)d_ws;

    hipMemsetAsync(d_ws, 0, 512 * sizeof(float), stream);
    moe_gate_main<<<T_TOKENS / TPB, 512, 0, stream>>>(x, wgt, out, gacc);
    moe_gate_aux<<<1, 256, 0, stream>>>(gacc, out);
}

// Round 2
// 305.150 us; speedup vs baseline: 1.8854x; 1.8854x over previous
//
#include <hip/hip_runtime.h>
#include <math.h>

// CRITICAL: no FMA contraction anywhere — we are bit-replicating numpy's
// SSE (no-FMA) float32 einsum inner loop.
#pragma clang fp contract(off)

#define T_TOKENS 16384
#define HDIM 2048
#define NEXP 64
#define TOPK 6
#define SEQ 4096
#define TPB 32          // tokens per block
#define KC 64           // k-chunk
#define WS 68           // padded LDS stride for W tile
#define XS 68           // padded LDS stride for X tile
#define LGS 65          // padded stride for logits
#define PS 65           // padded stride for probs

// numpy einsum contig_two micro-step (SSE3 baseline, 4 lanes, no FMA):
// per 16-element block: vacc[l] = a0[l]*b0[l] + (a1[l]*b1[l] + (a2[l]*b2[l] + (a3[l]*b3[l] + vacc[l])))
__device__ __forceinline__ void np_upd(const float4& w0, const float4& w1,
                                       const float4& w2, const float4& w3,
                                       const float4& x0, const float4& x1,
                                       const float4& x2, const float4& x3,
                                       float acc[4])
{
    acc[0] = w0.x*x0.x + (w1.x*x1.x + (w2.x*x2.x + (w3.x*x3.x + acc[0])));
    acc[1] = w0.y*x0.y + (w1.y*x1.y + (w2.y*x2.y + (w3.y*x3.y + acc[1])));
    acc[2] = w0.z*x0.z + (w1.z*x1.z + (w2.z*x2.z + (w3.z*x3.z + acc[2])));
    acc[3] = w0.w*x0.w + (w1.w*x1.w + (w2.w*x2.w + (w3.w*x3.w + acc[3])));
}

// 512 threads = 8 waves; each thread: 1 token row x 4 experts.
// Grid 512 blocks -> 2 blocks/CU, 16 waves/CU (2x the previous 8).
__global__ __launch_bounds__(512, 4) void moe_gate_main(
    const float* __restrict__ x, const float* __restrict__ wgt,
    float* __restrict__ out, float* __restrict__ gacc)
{
    __shared__ float w_lds[NEXP * WS];    // 17408 B
    __shared__ float x_lds[TPB * XS];     //  8704 B
    __shared__ float lg[TPB * LGS];       //  8320 B  fp32 logits (np bit-exact)
    __shared__ float probs[TPB * PS];     //  8320 B
    __shared__ float psum[8 * NEXP];      //  2048 B
    __shared__ int   cnt[NEXP];

    const int tid  = threadIdx.x;
    const int bid  = blockIdx.x;
    const int tb   = bid * TPB;
    const int b    = tb / SEQ;

    const int lane = tid & 63;
    const int wv   = tid >> 6;       // 0..7
    const int le   = lane & 15;      // expert sub-index
    const int g    = lane >> 4;      // 0..3
    const int trow = wv * 4 + g;     // token row 0..31

    // acc[expert_j][simd_lane]
    float acc[4][4];
    #pragma unroll
    for (int j = 0; j < 4; ++j)
        #pragma unroll
        for (int l = 0; l < 4; ++l) acc[j][l] = 0.f;

    for (int c = 0; c < HDIM / KC; ++c) {
        const int k0 = c * KC;
        // W tile: 64 experts x 16 slots(16B) = 1024 slots, 512 thr -> 2 rounds
        #pragma unroll
        for (int i = 0; i < 2; ++i) {
            int idx = i * 512 + tid;
            int e = idx >> 4, c4 = idx & 15;
            float4 v = *reinterpret_cast<const float4*>(&wgt[e * HDIM + k0 + c4 * 4]);
            *reinterpret_cast<float4*>(&w_lds[e * WS + c4 * 4]) = v;
        }
        // X tile: 32 rows x 16 slots = 512 slots -> 1 round
        {
            int t = tid >> 4, c4 = tid & 15;
            float4 v = *reinterpret_cast<const float4*>(&x[(size_t)(tb + t) * HDIM + k0 + c4 * 4]);
            *reinterpret_cast<float4*>(&x_lds[t * XS + c4 * 4]) = v;
        }
        __syncthreads();

        // k ascending in blocks of 16 (matches numpy's loop order)
        #pragma unroll
        for (int b16 = 0; b16 < 4; ++b16) {
            const int kb = b16 * 16;
            float4 xa[4];
            #pragma unroll
            for (int j = 0; j < 4; ++j)
                xa[j] = *reinterpret_cast<const float4*>(&x_lds[trow * XS + kb + j * 4]);
            #pragma unroll
            for (int je = 0; je < 4; ++je) {
                const float* wr = &w_lds[(le + 16 * je) * WS + kb];
                float4 w0 = *reinterpret_cast<const float4*>(wr);
                float4 w1 = *reinterpret_cast<const float4*>(wr + 4);
                float4 w2 = *reinterpret_cast<const float4*>(wr + 8);
                float4 w3 = *reinterpret_cast<const float4*>(wr + 12);
                np_upd(w0, w1, w2, w3, xa[0], xa[1], xa[2], xa[3], acc[je]);
            }
        }
        __syncthreads();
    }

    // horizontal reduce exactly like npyv_sum_f32 (SSE3 hadd): (v0+v1)+(v2+v3)
    #pragma unroll
    for (int je = 0; je < 4; ++je) {
        float v = (acc[je][0] + acc[je][1]) + (acc[je][2] + acc[je][3]);
        lg[trow * LGS + le + 16 * je] = v;
    }
    if (tid < NEXP) cnt[tid] = 0;
    __syncthreads();

    // ---- softmax per token (threads 0..31), fp32 like np
    if (tid < TPB) {
        const int t = tid;
        float mx = lg[t * LGS];
        for (int e = 1; e < NEXP; ++e) { float v = lg[t * LGS + e]; if (v > mx) mx = v; }
        for (int e = 0; e < NEXP; ++e)
            probs[t * PS + e] = expf(lg[t * LGS + e] - mx);
        // numpy pairwise sum, n=64: 8 strided accumulators then paired combine
        float r[8];
        #pragma unroll
        for (int j = 0; j < 8; ++j) r[j] = probs[t * PS + j];
        for (int i = 8; i < 64; i += 8)
            #pragma unroll
            for (int j = 0; j < 8; ++j) r[j] += probs[t * PS + i + j];
        float S = ((r[0] + r[1]) + (r[2] + r[3])) + ((r[4] + r[5]) + (r[6] + r[7]));
        for (int e = 0; e < NEXP; ++e) probs[t * PS + e] = probs[t * PS + e] / S;
    }
    __syncthreads();

    // ---- partial per-expert score sums (aux loss), all 512 threads
    {
        const int e = tid & 63, q = tid >> 6;   // q = 0..7, 4 tokens each
        float s = 0.f;
        for (int t = q * 4; t < q * 4 + 4; ++t) s += probs[t * PS + e];
        psum[q * 64 + e] = s;
    }
    __syncthreads();

    if (tid < TPB) {
        // ---- top-6 on fp32 probs, strict > ascending scan (tie -> lowest index)
        const int t = tid;
        const int gt = tb + t;
        float pv[TOPK]; int pi[TOPK];
        for (int r = 0; r < TOPK; ++r) {
            float bv = -1.f; int be = 0;
            for (int e = 0; e < NEXP; ++e) {
                float v = probs[t * PS + e];
                if (v > bv) { bv = v; be = e; }
            }
            probs[t * PS + be] = -1.f;
            pv[r] = bv; pi[r] = be;
            atomicAdd(&cnt[be], 1);
        }
        float wsum = pv[0];
        #pragma unroll
        for (int r = 1; r < TOPK; ++r) wsum += pv[r];
        wsum += 1e-20f;
        #pragma unroll
        for (int r = 0; r < TOPK; ++r) {
            out[(size_t)gt * TOPK + r] = (float)pi[r];
            out[(size_t)T_TOKENS * TOPK + (size_t)gt * TOPK + r] = pv[r] / wsum;
        }
    } else if (tid >= 64 && tid < 128) {
        const int e = tid - 64;
        float s = 0.f;
        #pragma unroll
        for (int q = 0; q < 8; ++q) s += psum[q * 64 + e];
        atomicAdd(&gacc[b * 64 + e], s);
    }
    __syncthreads();
    if (tid < NEXP) {
        atomicAdd(&gacc[256 + b * 64 + tid], (float)cnt[tid]);
    }
}

__global__ __launch_bounds__(256) void moe_gate_aux(
    const float* __restrict__ gacc, float* __restrict__ out)
{
    __shared__ float red[4];
    const int tid = threadIdx.x;
    float v = gacc[256 + tid] * gacc[tid];
    #pragma unroll
    for (int o = 32; o > 0; o >>= 1) v += __shfl_down(v, o, 64);
    if ((tid & 63) == 0) red[tid >> 6] = v;
    __syncthreads();
    if (tid == 0) {
        float tot = red[0] + red[1] + red[2] + red[3];
        const float scale = (64.0f / (4096.0f * 6.0f)) / 4096.0f;
        out[2 * T_TOKENS * TOPK] = 1e-3f * (tot * scale) * 0.25f;
    }
}

extern "C" void kernel_launch(void* const* d_in, const int* in_sizes, int n_in,
                              void* d_out, int out_size, void* d_ws, size_t ws_size,
                              hipStream_t stream) {
    const float* x   = (const float*)d_in[0];
    const float* wgt = (const float*)d_in[1];
    float* out  = (float*)d_out;
    float* gacc = (float*)d_ws;

    hipMemsetAsync(d_ws, 0, 512 * sizeof(float), stream);
    moe_gate_main<<<T_TOKENS / TPB, 512, 0, stream>>>(x, wgt, out, gacc);
    moe_gate_aux<<<1, 256, 0, stream>>>(gacc, out);
}